// Round 7
// baseline (101.782 us; speedup 1.0000x reference)
//
#include <hip/hip_runtime.h>

// EquivariantDense: out[b, i*O4+o] = sum_j sum_k w_{j+1}[b,o,k] * x[b, ((i+j)%4)*K + k]
// B=8, O4=1024, K=4096, N=4*K=16384. Output (B, 4*O4) fp32.
//
// R7: max-occupancy streaming shape (copy-ubench mimic). K split into 4
// slices of 1024; grid = (256 otiles, 4 slices, 8 b) = 8192 small blocks,
// 16 KiB LDS x-slice each -> 8 blocks/CU = 32 waves/CU, minimal VGPR.
// Each block computes slice-partials and atomicAdd's 16 fp32 outputs.
// Output zeroed each call via hipMemsetAsync (graph-capture legal).

#define B_DIM 8
#define O4_DIM 1024
#define K_DIM 4096
#define N_DIM 16384
#define TILE_O 4
#define SLICES 4
#define SLICE_F4 256   // 1024 floats per quarter-slice = 256 float4

typedef float floatx4 __attribute__((ext_vector_type(4)));

__global__ __launch_bounds__(256) void eq_dense_slice_kernel(
    const float* __restrict__ x,
    const float* __restrict__ w1,
    const float* __restrict__ w2,
    const float* __restrict__ w3,
    const float* __restrict__ w4,
    float* __restrict__ out)
{
    const int ot   = blockIdx.x;        // o-tile
    const int s    = blockIdx.y;        // K-slice
    const int b    = blockIdx.z;
    const int o0   = ot * TILE_O;
    const int tid  = threadIdx.x;
    const int j    = tid >> 6;          // wave id = weight tensor
    const int lane = tid & 63;

    __shared__ floatx4 xs[4 * SLICE_F4];     // 16 KiB: slice s of all 4 quarters
    __shared__ float red[4][TILE_O][4];      // [j][o][m]

    // Stage x slice: quarter m, float4 index s*256 + t  (coalesced per quarter).
    {
        const floatx4* xg = reinterpret_cast<const floatx4*>(x + (size_t)b * N_DIM);
#pragma unroll
        for (int m = 0; m < 4; ++m)
            xs[m * SLICE_F4 + tid] = xg[m * 1024 + s * SLICE_F4 + tid];
    }
    __syncthreads();

    const float* wsel = (j == 0) ? w1 : (j == 1) ? w2 : (j == 2) ? w3 : w4;
    // float4 base of row (b, o0) at slice s
    const floatx4* wbase = reinterpret_cast<const floatx4*>(
        wsel + ((size_t)b * O4_DIM + o0) * K_DIM) + s * SLICE_F4;

    float acc[TILE_O][4];
#pragma unroll
    for (int o = 0; o < TILE_O; ++o)
#pragma unroll
        for (int m = 0; m < 4; ++m)
            acc[o][m] = 0.0f;

    // 256 float4 per row-slice; 64 lanes -> 4 iterations; 4 rows.
#pragma unroll
    for (int it = 0; it < 4; ++it) {
        const int idx = it * 64 + lane;
        floatx4 wv[TILE_O];
#pragma unroll
        for (int o = 0; o < TILE_O; ++o)
            wv[o] = wbase[o * 1024 + idx];
        floatx4 xv[4];
#pragma unroll
        for (int m = 0; m < 4; ++m)
            xv[m] = xs[m * SLICE_F4 + idx];
#pragma unroll
        for (int o = 0; o < TILE_O; ++o)
#pragma unroll
            for (int m = 0; m < 4; ++m) {
                acc[o][m] += wv[o].x * xv[m].x;
                acc[o][m] += wv[o].y * xv[m].y;
                acc[o][m] += wv[o].z * xv[m].z;
                acc[o][m] += wv[o].w * xv[m].w;
            }
    }

    // Wave-level butterfly reduction of all 16 accumulators.
#pragma unroll
    for (int o = 0; o < TILE_O; ++o)
#pragma unroll
        for (int m = 0; m < 4; ++m) {
            float v = acc[o][m];
            v += __shfl_xor(v, 32, 64);
            v += __shfl_xor(v, 16, 64);
            v += __shfl_xor(v, 8, 64);
            v += __shfl_xor(v, 4, 64);
            v += __shfl_xor(v, 2, 64);
            v += __shfl_xor(v, 1, 64);
            acc[o][m] = v;
        }

    if (lane == 0) {
#pragma unroll
        for (int o = 0; o < TILE_O; ++o)
#pragma unroll
            for (int m = 0; m < 4; ++m)
                red[j][o][m] = acc[o][m];
    }
    __syncthreads();

    // Slice-partial of out[b, i*O4 + o0+o] = sum_j red[j][o][(i+j)&3]
    if (tid < 16) {
        const int o = tid & 3;
        const int i = tid >> 2;
        float v = 0.0f;
#pragma unroll
        for (int jj = 0; jj < 4; ++jj)
            v += red[jj][o][(i + jj) & 3];
        atomicAdd(&out[(size_t)b * (4 * O4_DIM) + (size_t)i * O4_DIM + (o0 + o)], v);
    }
}

extern "C" void kernel_launch(void* const* d_in, const int* in_sizes, int n_in,
                              void* d_out, int out_size, void* d_ws, size_t ws_size,
                              hipStream_t stream) {
    const float* x  = (const float*)d_in[0];
    const float* w1 = (const float*)d_in[1];
    const float* w2 = (const float*)d_in[2];
    const float* w3 = (const float*)d_in[3];
    const float* w4 = (const float*)d_in[4];
    float* out = (float*)d_out;

    // Zero output (atomic accumulation target). Async memset is capture-legal.
    hipMemsetAsync(out, 0, (size_t)out_size * sizeof(float), stream);

    dim3 grid(O4_DIM / TILE_O, SLICES, B_DIM);  // (256, 4, 8) = 8192 blocks
    dim3 block(256);
    eq_dense_slice_kernel<<<grid, block, 0, stream>>>(x, w1, w2, w3, w4, out);
}

// Round 8
// 93.812 us; speedup vs baseline: 1.0850x; 1.0850x over previous
//
#include <hip/hip_runtime.h>

// EquivariantDense: out[b, i*O4+o] = sum_j sum_k w_{j+1}[b,o,k] * x[b, ((i+j)%4)*K + k]
// B=8, O4=1024, K=4096, N=4*K=16384. Output (B, 4*O4) fp32.
//
// FINAL (= R4, best of 5 structural variants at 94.3 us):
//   - 256-thread blocks, one block per (b, 4-row o-tile); wave j owns w_{j+1}.
//   - x[b] (64 KiB) staged once in LDS -> inner-loop x reads use the DS pipe
//     (lgkmcnt), leaving the VMEM pipe/waitcnt chain pure for the weight stream.
//   - Each lane: 4 coalesced float4 weight-row streams, 16 fp32 accumulators;
//     butterfly __shfl_xor reduce; 4-wave LDS combine; 16 outputs/block.
// Roofline: 537 MB irreducible weight read / 94.3 us = 5.70 TB/s combined
// L3+HBM service = ~90% of the measured 6.29 TB/s fabric ceiling. Occupancy
// (21 vs 42%), stream count (1 vs 4/wave), NT hints, K-split + full-occupancy
// shapes are all null or worse -> memory-system service-rate bound.

#define B_DIM 8
#define O4_DIM 1024
#define K_DIM 4096
#define N_DIM 16384
#define TILE_O 4

typedef float floatx4 __attribute__((ext_vector_type(4)));

__global__ __launch_bounds__(256) void eq_dense_kernel(
    const float* __restrict__ x,
    const float* __restrict__ w1,
    const float* __restrict__ w2,
    const float* __restrict__ w3,
    const float* __restrict__ w4,
    float* __restrict__ out)
{
    const int b    = blockIdx.y;
    const int o0   = blockIdx.x * TILE_O;
    const int tid  = threadIdx.x;
    const int j    = tid >> 6;   // wave id = which weight tensor
    const int lane = tid & 63;

    __shared__ floatx4 xs[N_DIM / 4];        // 64 KiB: all of x[b]
    __shared__ float red[4][TILE_O][4];      // [j][o][m]

    // Stage x[b] into LDS: 4096 float4 / 256 threads = 16 per thread, coalesced.
    {
        const floatx4* xg = reinterpret_cast<const floatx4*>(x + (size_t)b * N_DIM);
#pragma unroll
        for (int r = 0; r < 16; ++r)
            xs[r * 256 + tid] = xg[r * 256 + tid];
    }
    __syncthreads();

    const float* wsel = (j == 0) ? w1 : (j == 1) ? w2 : (j == 2) ? w3 : w4;
    const floatx4* wbase = reinterpret_cast<const floatx4*>(
        wsel + ((size_t)b * O4_DIM + o0) * K_DIM);

    float acc[TILE_O][4];
#pragma unroll
    for (int o = 0; o < TILE_O; ++o)
#pragma unroll
        for (int m = 0; m < 4; ++m)
            acc[o][m] = 0.0f;

    // K_DIM/4 = 1024 float4 per row; 64 lanes -> 16 iterations.
#pragma unroll 4
    for (int it = 0; it < 16; ++it) {
        const int idx = it * 64 + lane;
        floatx4 wv[TILE_O];
#pragma unroll
        for (int o = 0; o < TILE_O; ++o)
            wv[o] = wbase[o * 1024 + idx];      // VMEM: pure weight stream
        floatx4 xv[4];
#pragma unroll
        for (int m = 0; m < 4; ++m)
            xv[m] = xs[m * 1024 + idx];         // DS pipe, conflict-free b128
#pragma unroll
        for (int o = 0; o < TILE_O; ++o)
#pragma unroll
            for (int m = 0; m < 4; ++m) {
                acc[o][m] += wv[o].x * xv[m].x;
                acc[o][m] += wv[o].y * xv[m].y;
                acc[o][m] += wv[o].z * xv[m].z;
                acc[o][m] += wv[o].w * xv[m].w;
            }
    }

    // Wave-level butterfly reduction of all 16 accumulators (64 lanes).
#pragma unroll
    for (int o = 0; o < TILE_O; ++o)
#pragma unroll
        for (int m = 0; m < 4; ++m) {
            float v = acc[o][m];
            v += __shfl_xor(v, 32, 64);
            v += __shfl_xor(v, 16, 64);
            v += __shfl_xor(v, 8, 64);
            v += __shfl_xor(v, 4, 64);
            v += __shfl_xor(v, 2, 64);
            v += __shfl_xor(v, 1, 64);
            acc[o][m] = v;
        }

    __syncthreads();  // red[] write barrier
    if (lane == 0) {
#pragma unroll
        for (int o = 0; o < TILE_O; ++o)
#pragma unroll
            for (int m = 0; m < 4; ++m)
                red[j][o][m] = acc[o][m];
    }
    __syncthreads();

    // out[b, i*O4 + o0+o] = sum_j red[j][o][(i+j)&3]
    if (tid < TILE_O * 4) {
        const int o = tid & (TILE_O - 1);
        const int i = tid >> 2;
        float v = 0.0f;
#pragma unroll
        for (int jj = 0; jj < 4; ++jj)
            v += red[jj][o][(i + jj) & 3];
        out[(size_t)b * (4 * O4_DIM) + (size_t)i * O4_DIM + (o0 + o)] = v;
    }
}

extern "C" void kernel_launch(void* const* d_in, const int* in_sizes, int n_in,
                              void* d_out, int out_size, void* d_ws, size_t ws_size,
                              hipStream_t stream) {
    const float* x  = (const float*)d_in[0];
    const float* w1 = (const float*)d_in[1];
    const float* w2 = (const float*)d_in[2];
    const float* w3 = (const float*)d_in[3];
    const float* w4 = (const float*)d_in[4];
    float* out = (float*)d_out;

    dim3 grid(O4_DIM / TILE_O, B_DIM);  // (256, 8) = 2048 blocks
    dim3 block(256);
    eq_dense_kernel<<<grid, block, 0, stream>>>(x, w1, w2, w3, w4, out);
}